// Round 2
// baseline (744.419 us; speedup 1.0000x reference)
//
#include <hip/hip_runtime.h>
#include <hip/hip_bf16.h>

// GCN layer: out = relu( (D^-1/2 A D^-1/2) (x @ w) + b )
//
// R7 (from R6's 617 us / R5's 595 us):
//   - resort kernel DELETED (R6 evidence: it cost ~20 us while saving aggb
//     only 5 us -- the in-aggb counting sort is hidden under the gather
//     path saturation). aggb reverts to R5's self-sorting version.
//   - deg_kernel restored (dinv needed before gemm).
//   - gemm staging pack2 -> v_cvt_pk_bf16_f32 (1 instr vs ~10, same RNE).
//   - MEASUREMENT: gemm launched 3x (idempotent). gemm_us = (total-600)/2.
//     Resolves whether gemm is the hidden chunk of the 373 us non-aggb time
//     (top-5 table only shows the 5 aggb instances, all ~249 us).
// aggb floor: 753 MB past-L2 gather at ~3.5-4 TB/s path cap = ~244-249 us.

#define DF   256   // D_FEAT == FILTERS == 256
#define RSH  7
#define RPB  128   // rows per bucket = 1<<RSH
#define CAP  4800  // LDS edge capacity per bucket (mean 4096, sd 64 -> 11 sigma)
#define CHUNK 8192 // edges per block in A1/A3
#define LSTR 40    // gemm LDS row stride in shorts (80 B; banks spread)

typedef __attribute__((ext_vector_type(8))) short short8;  // 8 x bf16
typedef __attribute__((ext_vector_type(4))) float f32x4;

__device__ __forceinline__ unsigned short f2bf(float f) {
    unsigned int u = __float_as_uint(f);
    unsigned int r = (u + 0x7fffu + ((u >> 16) & 1u)) >> 16;  // RNE
    return (unsigned short)r;
}
// v_cvt_pk_bf16_f32: D.lo = bf16(a) RNE, D.hi = bf16(b) RNE (gfx950)
__device__ __forceinline__ unsigned int pack2(float a, float b) {
    unsigned int r;
    asm("v_cvt_pk_bf16_f32 %0, %1, %2" : "=v"(r) : "v"(a), "v"(b));
    return r;
}
__device__ __forceinline__ float bflo(unsigned int u) { return __uint_as_float(u << 16); }
__device__ __forceinline__ float bfhi(unsigned int u) { return __uint_as_float(u & 0xffff0000u); }

// A1: per-block bucket histogram; layout bh1[bucket][block] so bscan reads coalesced.
__global__ __launch_bounds__(256) void bhist_kernel(const int* __restrict__ row,
                                                    int* __restrict__ bh1, int NB, int NBLK, int E) {
    __shared__ int hist[1024];
    int t = threadIdx.x;
    for (int i = t; i < NB; i += 256) hist[i] = 0;
    __syncthreads();
    int base = blockIdx.x * CHUNK;
    int end = base + CHUNK; if (end > E) end = E;
    for (int i = base + t; i < end; i += 256)
        atomicAdd(&hist[row[i] >> RSH], 1);
    __syncthreads();
    for (int i = t; i < NB; i += 256)
        bh1[(size_t)i * NBLK + blockIdx.x] = hist[i];
}

// A2: per bucket (blockIdx), exclusive scan over NBLK block counts (NBLK <= 512).
// Reads bh1[b][e] coalesced, writes bh2[e][b] (strided stores, fire-and-forget).
__global__ __launch_bounds__(256) void bscan_kernel(const int* __restrict__ bh1,
                                                    int* __restrict__ bh2,
                                                    int* __restrict__ buckettot, int NB, int NBLK) {
    __shared__ int ps[256];
    int b = blockIdx.x, t = threadIdx.x;
    int e0 = 2 * t, e1 = 2 * t + 1;
    int v0 = (e0 < NBLK) ? bh1[(size_t)b * NBLK + e0] : 0;
    int v1 = (e1 < NBLK) ? bh1[(size_t)b * NBLK + e1] : 0;
    int tsum = v0 + v1;
    ps[t] = tsum;
    __syncthreads();
    for (int off = 1; off < 256; off <<= 1) {
        int v = (t >= off) ? ps[t - off] : 0;
        __syncthreads();
        ps[t] += v;
        __syncthreads();
    }
    int pre = ps[t] - tsum;  // exclusive
    if (e0 < NBLK) bh2[(size_t)e0 * NB + b] = pre;
    if (e1 < NBLK) bh2[(size_t)e1 * NB + b] = pre + v0;
    if (t == 255) buckettot[b] = ps[255];
}

// A2b: single block, exclusive scan of buckettot[0..NB) -> bucket_base[0..NB]
__global__ __launch_bounds__(1024) void btot_kernel(const int* __restrict__ buckettot,
                                                    int* __restrict__ bucket_base, int NB) {
    __shared__ int ps[1024];
    int t = threadIdx.x;
    int v = (t < NB) ? buckettot[t] : 0;
    ps[t] = v;
    __syncthreads();
    for (int off = 1; off < 1024; off <<= 1) {
        int u = (t >= off) ? ps[t - off] : 0;
        __syncthreads();
        ps[t] += u;
        __syncthreads();
    }
    if (t < NB) bucket_base[t] = ps[t] - v;
    if (t == 1023) bucket_base[NB] = ps[1023];
}

// A3: scatter edges into buckets. Reads bh2[blk][bucket] coalesced; LDS atomics only.
__global__ __launch_bounds__(256) void bscatter_kernel(const int* __restrict__ row,
                                                       const int* __restrict__ col,
                                                       const float* __restrict__ vals,
                                                       const int* __restrict__ bh2,
                                                       const int* __restrict__ bucket_base,
                                                       int2* __restrict__ bedge, int NB, int E) {
    __shared__ int loff[1024];
    int t = threadIdx.x, blk = blockIdx.x;
    for (int i = t; i < NB; i += 256)
        loff[i] = bucket_base[i] + bh2[(size_t)blk * NB + i];
    __syncthreads();
    int base = blk * CHUNK;
    int end = base + CHUNK; if (end > E) end = E;
    for (int i = base + t; i < end; i += 256) {
        int r = row[i];
        int p = atomicAdd(&loff[r >> RSH], 1);
        bedge[p] = make_int2(((r & (RPB - 1)) << 17) | col[i], __float_as_int(vals[i]));
    }
}

// Deg: block per bucket; LDS float accumulators; fused dinv. (R5-proven)
__global__ __launch_bounds__(256) void deg_kernel(const int2* __restrict__ bedge,
                                                  const int* __restrict__ bucket_base,
                                                  float* __restrict__ dinv, int N) {
    __shared__ float acc[RPB];
    int b = blockIdx.x, t = threadIdx.x;
    if (t < RPB) acc[t] = 0.f;
    __syncthreads();
    int s = bucket_base[b], e = bucket_base[b + 1];
    for (int i = s + t; i < e; i += 256) {
        int2 ed = bedge[i];
        atomicAdd(&acc[ed.x >> 17], __int_as_float(ed.y));
    }
    __syncthreads();
    if (t < RPB) {
        int r = b * RPB + t;
        if (r < N) {
            float d = acc[t];
            dinv[r] = (d > 0.f) ? (1.0f / sqrtf(d)) : 0.f;
        }
    }
}

// w[256][256] -> wT[256][256] (one-time, 256 KB)
__global__ __launch_bounds__(256) void transpose_kernel(const float* __restrict__ w,
                                                        float* __restrict__ wT) {
    __shared__ float tile[32][33];
    int bx = blockIdx.x * 32, by = blockIdx.y * 32;
    int tx = threadIdx.x, ty = threadIdx.y;  // dim(32,8)
    for (int j = ty; j < 32; j += 8) tile[j][tx] = w[(by + j) * DF + bx + tx];
    __syncthreads();
    for (int j = ty; j < 32; j += 8) wT[(bx + j) * DF + by + tx] = tile[tx][j];
}

// MFMA bf16 GEMM: h'[r,:] = bf16( dinv[r] * (x[r,:] @ w) )
// 128x256 tile (x read ONCE), BK=32, 4 waves in 2x2, each wave 64x128 =
// 4x8 MFMA 16x16x32. LDS stride 40 shorts breaks bank conflicts.
__global__ __launch_bounds__(256, 2) void gemm_kernel(const float* __restrict__ x,
                                                      const float* __restrict__ wT,
                                                      const float* __restrict__ dinv,
                                                      unsigned short* __restrict__ h, int N) {
    __shared__ unsigned short Al[128 * LSTR];   // 10 KB
    __shared__ unsigned short Bl[256 * LSTR];   // 20 KB
    int tid = threadIdx.x;
    int by = blockIdx.x;
    int wv = tid >> 6, lane = tid & 63;
    int wr = wv >> 1, wc = wv & 1;
    int q = lane >> 4, mi = lane & 15;

    f32x4 acc[4][8];
#pragma unroll
    for (int i = 0; i < 4; ++i)
#pragma unroll
        for (int j = 0; j < 8; ++j) acc[i][j] = (f32x4){0.f, 0.f, 0.f, 0.f};

    int srow = tid >> 1;           // 0..127
    int sseg = (tid & 1) * 16;     // k offset 0 or 16
    int axrow = by * 128 + srow; if (axrow >= N) axrow = N - 1;
    const float* ax = x + (long)axrow * DF + sseg;
    const float* bxp = wT + (long)tid * DF;         // thread t stages wT row t
    unsigned short* Aw = &Al[srow * LSTR + sseg];
    unsigned short* Bw = &Bl[tid * LSTR];

    for (int kk = 0; kk < DF; kk += 32) {
        float4 a0 = *(const float4*)(ax + kk);
        float4 a1 = *(const float4*)(ax + kk + 4);
        float4 a2 = *(const float4*)(ax + kk + 8);
        float4 a3 = *(const float4*)(ax + kk + 12);
        float4 b0 = *(const float4*)(bxp + kk);
        float4 b1 = *(const float4*)(bxp + kk + 4);
        float4 b2 = *(const float4*)(bxp + kk + 8);
        float4 b3 = *(const float4*)(bxp + kk + 12);
        float4 b4 = *(const float4*)(bxp + kk + 16);
        float4 b5 = *(const float4*)(bxp + kk + 20);
        float4 b6 = *(const float4*)(bxp + kk + 24);
        float4 b7 = *(const float4*)(bxp + kk + 28);
        __syncthreads();   // previous iteration's frag reads complete
        uint4 pa;
        pa.x = pack2(a0.x, a0.y); pa.y = pack2(a0.z, a0.w);
        pa.z = pack2(a1.x, a1.y); pa.w = pack2(a1.z, a1.w);
        *(uint4*)Aw = pa;
        pa.x = pack2(a2.x, a2.y); pa.y = pack2(a2.z, a2.w);
        pa.z = pack2(a3.x, a3.y); pa.w = pack2(a3.z, a3.w);
        *(uint4*)(Aw + 8) = pa;
        uint4 pb;
        pb.x = pack2(b0.x, b0.y); pb.y = pack2(b0.z, b0.w);
        pb.z = pack2(b1.x, b1.y); pb.w = pack2(b1.z, b1.w);
        *(uint4*)Bw = pb;
        pb.x = pack2(b2.x, b2.y); pb.y = pack2(b2.z, b2.w);
        pb.z = pack2(b3.x, b3.y); pb.w = pack2(b3.z, b3.w);
        *(uint4*)(Bw + 8) = pb;
        pb.x = pack2(b4.x, b4.y); pb.y = pack2(b4.z, b4.w);
        pb.z = pack2(b5.x, b5.y); pb.w = pack2(b5.z, b5.w);
        *(uint4*)(Bw + 16) = pb;
        pb.x = pack2(b6.x, b6.y); pb.y = pack2(b6.z, b6.w);
        pb.z = pack2(b7.x, b7.y); pb.w = pack2(b7.z, b7.w);
        *(uint4*)(Bw + 24) = pb;
        __syncthreads();   // tiles ready

        short8 af[4];
#pragma unroll
        for (int i = 0; i < 4; ++i)
            af[i] = *(const short8*)&Al[(wr * 64 + i * 16 + mi) * LSTR + q * 8];
#pragma unroll
        for (int j = 0; j < 8; ++j) {
            short8 bfj = *(const short8*)&Bl[(wc * 128 + j * 16 + mi) * LSTR + q * 8];
#pragma unroll
            for (int i = 0; i < 4; ++i)
                acc[i][j] = __builtin_amdgcn_mfma_f32_16x16x32_bf16(af[i], bfj, acc[i][j], 0, 0, 0);
        }
    }

    // C/D layout: col = lane&15, row = (lane>>4)*4 + reg   [verified m89/m91]
#pragma unroll
    for (int i = 0; i < 4; ++i) {
        int base_row = by * 128 + wr * 64 + i * 16 + q * 4;
#pragma unroll
        for (int r = 0; r < 4; ++r) {
            int rg = base_row + r;
            if (rg < N) {
                float dv = dinv[rg];
#pragma unroll
                for (int j = 0; j < 8; ++j) {
                    int cg = wc * 128 + j * 16 + mi;
                    h[(long)rg * DF + cg] = f2bf(dv * acc[i][j][r]);
                }
            }
        }
    }
}

// aggB: block per bucket. Counting-sort bucket edges into LDS, then one wave
// per row: split-wave gather. (R5-proven version: sort is hidden under the
// path-saturated gather.)
__global__ __launch_bounds__(256) void aggb_kernel(const unsigned short* __restrict__ h,
                                                   const int2* __restrict__ bedge,
                                                   const int* __restrict__ bucket_base,
                                                   const float* __restrict__ dinv,
                                                   const float* __restrict__ bias,
                                                   float* __restrict__ out, int N) {
    __shared__ int2 ledge[CAP];
    __shared__ int cnt[RPB];
    __shared__ int lrs[RPB + 1];
    __shared__ int lfill[RPB];
    int b = blockIdx.x, t = threadIdx.x;
    int s = bucket_base[b], e = bucket_base[b + 1];
    int tot = e - s;
    int cap_end = s + (tot < CAP ? tot : CAP);
    if (t < RPB) { cnt[t] = 0; lfill[t] = 0; }
    __syncthreads();
    // phase 1: count by local row
    for (int i = s + t; i < cap_end; i += 256)
        atomicAdd(&cnt[bedge[i].x >> 17], 1);
    __syncthreads();
    // exclusive scan cnt -> lrs (lrs[RPB] = total)
    int myc = 0;
    if (t < RPB) { myc = cnt[t]; lrs[t] = myc; }
    __syncthreads();
    for (int off = 1; off < RPB; off <<= 1) {
        int v = (t < RPB && t >= off) ? lrs[t - off] : 0;
        __syncthreads();
        if (t < RPB) lrs[t] += v;
        __syncthreads();
    }
    if (t < RPB) {
        int iv = lrs[t];
        lrs[t] = iv - myc;
        if (t == RPB - 1) lrs[RPB] = iv;
    }
    __syncthreads();
    // phase 2: scatter into sorted LDS (L2-hot re-read)
    for (int i = s + t; i < cap_end; i += 256) {
        int2 ed = bedge[i];
        int rl = ed.x >> 17;
        int p = lrs[rl] + atomicAdd(&lfill[rl], 1);
        ledge[p] = make_int2(ed.x & 0x1FFFF, ed.y);
    }
    __syncthreads();
    // phase 3: wave per row
    int wv = t >> 6, lane = t & 63;
    int half = lane >> 5;
    int fl = (lane & 31) * 8;
    const unsigned short* hp = h + fl;
    for (int lr = wv; lr < RPB; lr += 4) {
        int r = b * RPB + lr;
        if (r >= N) break;
        int rs = lrs[lr], re = lrs[lr + 1];
        float a0 = 0, a1 = 0, a2 = 0, a3 = 0, a4 = 0, a5 = 0, a6 = 0, a7 = 0;
        int i = rs + half;
        for (; i + 6 < re; i += 8) {
            int2 e0 = ledge[i], e1 = ledge[i + 2], e2 = ledge[i + 4], e3 = ledge[i + 6];
            uint4 u0 = *(const uint4*)(hp + (long)e0.x * DF);
            uint4 u1 = *(const uint4*)(hp + (long)e1.x * DF);
            uint4 u2 = *(const uint4*)(hp + (long)e2.x * DF);
            uint4 u3 = *(const uint4*)(hp + (long)e3.x * DF);
            float v0 = __int_as_float(e0.y), v1 = __int_as_float(e1.y);
            float v2 = __int_as_float(e2.y), v3 = __int_as_float(e3.y);
            a0 += v0 * bflo(u0.x) + v1 * bflo(u1.x) + v2 * bflo(u2.x) + v3 * bflo(u3.x);
            a1 += v0 * bfhi(u0.x) + v1 * bfhi(u1.x) + v2 * bfhi(u2.x) + v3 * bfhi(u3.x);
            a2 += v0 * bflo(u0.y) + v1 * bflo(u1.y) + v2 * bflo(u2.y) + v3 * bflo(u3.y);
            a3 += v0 * bfhi(u0.y) + v1 * bfhi(u1.y) + v2 * bfhi(u2.y) + v3 * bfhi(u3.y);
            a4 += v0 * bflo(u0.z) + v1 * bflo(u1.z) + v2 * bflo(u2.z) + v3 * bflo(u3.z);
            a5 += v0 * bfhi(u0.z) + v1 * bfhi(u1.z) + v2 * bfhi(u2.z) + v3 * bfhi(u3.z);
            a6 += v0 * bflo(u0.w) + v1 * bflo(u1.w) + v2 * bflo(u2.w) + v3 * bflo(u3.w);
            a7 += v0 * bfhi(u0.w) + v1 * bfhi(u1.w) + v2 * bfhi(u2.w) + v3 * bfhi(u3.w);
        }
        for (; i < re; i += 2) {
            int2 e0 = ledge[i];
            float v0 = __int_as_float(e0.y);
            uint4 u0 = *(const uint4*)(hp + (long)e0.x * DF);
            a0 += v0 * bflo(u0.x); a1 += v0 * bfhi(u0.x);
            a2 += v0 * bflo(u0.y); a3 += v0 * bfhi(u0.y);
            a4 += v0 * bflo(u0.z); a5 += v0 * bfhi(u0.z);
            a6 += v0 * bflo(u0.w); a7 += v0 * bfhi(u0.w);
        }
        // overflow leftovers (normally empty): filter unsorted global tail
        for (int j = cap_end + half; j < e; j += 2) {
            int2 ed = bedge[j];
            if ((ed.x >> 17) == lr) {
                float v0 = __int_as_float(ed.y);
                uint4 u0 = *(const uint4*)(hp + (long)(ed.x & 0x1FFFF) * DF);
                a0 += v0 * bflo(u0.x); a1 += v0 * bfhi(u0.x);
                a2 += v0 * bflo(u0.y); a3 += v0 * bfhi(u0.y);
                a4 += v0 * bflo(u0.z); a5 += v0 * bfhi(u0.z);
                a6 += v0 * bflo(u0.w); a7 += v0 * bfhi(u0.w);
            }
        }
        a0 += __shfl_xor(a0, 32); a1 += __shfl_xor(a1, 32);
        a2 += __shfl_xor(a2, 32); a3 += __shfl_xor(a3, 32);
        a4 += __shfl_xor(a4, 32); a5 += __shfl_xor(a5, 32);
        a6 += __shfl_xor(a6, 32); a7 += __shfl_xor(a7, 32);
        if (half == 0) {
            float dr = dinv[r];
            float4 b0 = *(const float4*)(bias + fl);
            float4 b1 = *(const float4*)(bias + fl + 4);
            float4 o0, o1;
            o0.x = fmaxf(fmaf(dr, a0, b0.x), 0.f);
            o0.y = fmaxf(fmaf(dr, a1, b0.y), 0.f);
            o0.z = fmaxf(fmaf(dr, a2, b0.z), 0.f);
            o0.w = fmaxf(fmaf(dr, a3, b0.w), 0.f);
            o1.x = fmaxf(fmaf(dr, a4, b1.x), 0.f);
            o1.y = fmaxf(fmaf(dr, a5, b1.y), 0.f);
            o1.z = fmaxf(fmaf(dr, a6, b1.z), 0.f);
            o1.w = fmaxf(fmaf(dr, a7, b1.w), 0.f);
            *(float4*)(out + (long)r * DF + fl) = o0;
            *(float4*)(out + (long)r * DF + fl + 4) = o1;
        }
    }
}

extern "C" void kernel_launch(void* const* d_in, const int* in_sizes, int n_in,
                              void* d_out, int out_size, void* d_ws, size_t ws_size,
                              hipStream_t stream) {
    const float* x   = (const float*)d_in[0];
    const int* erow  = (const int*)d_in[1];
    const int* ecol  = (const int*)d_in[2];
    const float* ev  = (const float*)d_in[3];
    const float* w   = (const float*)d_in[4];
    const float* b   = (const float*)d_in[5];
    float* out = (float*)d_out;

    int N = in_sizes[0] / DF;
    int E = in_sizes[1];
    int NB = (N + RPB - 1) >> RSH;          // 782 (<=1024 supported)
    int NBLK = (E + CHUNK - 1) / CHUNK;     // 391 (<=512 supported)

    char* ws = (char*)d_ws;
    size_t Ea8 = (((size_t)E * 8) + 255) & ~(size_t)255;         // bedge
    size_t Hs  = (((size_t)N * DF * 2) + 255) & ~(size_t)255;    // h
    size_t Na  = (((size_t)N * 4) + 255) & ~(size_t)255;

    // Layout (~77.5 MB total; bh1/bh2 alias h — dead before gemm):
    int2* bedge = (int2*)ws;
    char* reg2 = ws + Ea8;
    unsigned short* h = (unsigned short*)reg2;
    int* bh1 = (int*)reg2;                   // alias of h (A1..A3 only)
    int* bh2 = bh1 + (size_t)NB * NBLK;      // alias of h (A1..A3 only)
    char* reg3 = reg2 + Hs;
    float* wT = (float*)reg3;
    float* dinv = (float*)(reg3 + 262144);
    int* buckettot = (int*)(reg3 + 262144 + Na);
    int* bucket_base = (int*)(reg3 + 262144 + Na + 8192);

    bhist_kernel<<<NBLK, 256, 0, stream>>>(erow, bh1, NB, NBLK, E);
    bscan_kernel<<<NB, 256, 0, stream>>>(bh1, bh2, buckettot, NB, NBLK);
    btot_kernel<<<1, 1024, 0, stream>>>(buckettot, bucket_base, NB);
    bscatter_kernel<<<NBLK, 256, 0, stream>>>(erow, ecol, ev, bh2, bucket_base, bedge, NB, E);
    deg_kernel<<<NB, 256, 0, stream>>>(bedge, bucket_base, dinv, N);
    transpose_kernel<<<dim3(8, 8), dim3(32, 8), 0, stream>>>(w, wT);
    // MEASUREMENT: gemm launched 3x (idempotent: pure fn of x,wT,dinv).
    // gemm_us = (total_us - ~600)/2. Remove after the blind spot is resolved.
    gemm_kernel<<<dim3((N + 127) / 128), 256, 0, stream>>>(x, wT, dinv, h, N);
    gemm_kernel<<<dim3((N + 127) / 128), 256, 0, stream>>>(x, wT, dinv, h, N);
    gemm_kernel<<<dim3((N + 127) / 128), 256, 0, stream>>>(x, wT, dinv, h, N);
    aggb_kernel<<<NB, 256, 0, stream>>>(h, bedge, bucket_base, dinv, b, out, N);
}

// Round 4
// 590.664 us; speedup vs baseline: 1.2603x; 1.2603x over previous
//
#include <hip/hip_runtime.h>
#include <hip/hip_bf16.h>

// GCN layer: out = relu( (D^-1/2 A D^-1/2) (x @ w) + b )
//
// R9 = R8 retry (R8 bench died to a container-level infra failure, no
// counters; kernel audited: 94KB static LDS is legal on gfx950, bounds and
// barriers clean -> resubmitting unchanged to get the measurement).
//
// R8 theory (from R7's 3x-gemm probe + R5/R6/R7 diffs):
//   gemm ~74 us (structure-bound), aggb ~250 us (path-saturated floor),
//   prep+gaps ~270 us of which ~180-210 us is bscatter's per-instruction
//   scatter: 64 lanes -> 64 different bucket runs -> 64 line transactions
//   per store, at the ~23 G-transaction/s ceiling (R1-R4 evidence).
//   FIX: bscatter -> bsort_kernel: counting-sort the block's 8192 edges in
//   LDS (hist -> scan -> LDS scatter + slot->bucket map), then flush
//   sequentially: consecutive lanes write consecutive sorted slots, which
//   land in ~6 contiguous bucket runs per wave instr (~10-13 line
//   transactions vs 64). Global bedge layout identical; deg/gemm/aggb
//   untouched.

#define DF   256   // D_FEAT == FILTERS == 256
#define RSH  7
#define RPB  128   // rows per bucket = 1<<RSH
#define CAP  4800  // LDS edge capacity per bucket (mean 4096, sd 64 -> 11 sigma)
#define CHUNK 8192 // edges per block in A1/A3
#define LSTR 40    // gemm LDS row stride in shorts (80 B; banks spread)

typedef __attribute__((ext_vector_type(8))) short short8;  // 8 x bf16
typedef __attribute__((ext_vector_type(4))) float f32x4;

__device__ __forceinline__ unsigned short f2bf(float f) {
    unsigned int u = __float_as_uint(f);
    unsigned int r = (u + 0x7fffu + ((u >> 16) & 1u)) >> 16;  // RNE
    return (unsigned short)r;
}
// v_cvt_pk_bf16_f32: D.lo = bf16(a) RNE, D.hi = bf16(b) RNE (gfx950)
__device__ __forceinline__ unsigned int pack2(float a, float b) {
    unsigned int r;
    asm("v_cvt_pk_bf16_f32 %0, %1, %2" : "=v"(r) : "v"(a), "v"(b));
    return r;
}
__device__ __forceinline__ float bflo(unsigned int u) { return __uint_as_float(u << 16); }
__device__ __forceinline__ float bfhi(unsigned int u) { return __uint_as_float(u & 0xffff0000u); }

// A1: per-block bucket histogram; layout bh1[bucket][block] so bscan reads coalesced.
__global__ __launch_bounds__(256) void bhist_kernel(const int* __restrict__ row,
                                                    int* __restrict__ bh1, int NB, int NBLK, int E) {
    __shared__ int hist[1024];
    int t = threadIdx.x;
    for (int i = t; i < NB; i += 256) hist[i] = 0;
    __syncthreads();
    int base = blockIdx.x * CHUNK;
    int end = base + CHUNK; if (end > E) end = E;
    for (int i = base + t; i < end; i += 256)
        atomicAdd(&hist[row[i] >> RSH], 1);
    __syncthreads();
    for (int i = t; i < NB; i += 256)
        bh1[(size_t)i * NBLK + blockIdx.x] = hist[i];
}

// A2: per bucket (blockIdx), exclusive scan over NBLK block counts (NBLK <= 512).
// Reads bh1[b][e] coalesced, writes bh2[e][b] (strided stores, fire-and-forget).
__global__ __launch_bounds__(256) void bscan_kernel(const int* __restrict__ bh1,
                                                    int* __restrict__ bh2,
                                                    int* __restrict__ buckettot, int NB, int NBLK) {
    __shared__ int ps[256];
    int b = blockIdx.x, t = threadIdx.x;
    int e0 = 2 * t, e1 = 2 * t + 1;
    int v0 = (e0 < NBLK) ? bh1[(size_t)b * NBLK + e0] : 0;
    int v1 = (e1 < NBLK) ? bh1[(size_t)b * NBLK + e1] : 0;
    int tsum = v0 + v1;
    ps[t] = tsum;
    __syncthreads();
    for (int off = 1; off < 256; off <<= 1) {
        int v = (t >= off) ? ps[t - off] : 0;
        __syncthreads();
        ps[t] += v;
        __syncthreads();
    }
    int pre = ps[t] - tsum;  // exclusive
    if (e0 < NBLK) bh2[(size_t)e0 * NB + b] = pre;
    if (e1 < NBLK) bh2[(size_t)e1 * NB + b] = pre + v0;
    if (t == 255) buckettot[b] = ps[255];
}

// A2b: single block, exclusive scan of buckettot[0..NB) -> bucket_base[0..NB]
__global__ __launch_bounds__(1024) void btot_kernel(const int* __restrict__ buckettot,
                                                    int* __restrict__ bucket_base, int NB) {
    __shared__ int ps[1024];
    int t = threadIdx.x;
    int v = (t < NB) ? buckettot[t] : 0;
    ps[t] = v;
    __syncthreads();
    for (int off = 1; off < 1024; off <<= 1) {
        int u = (t >= off) ? ps[t - off] : 0;
        __syncthreads();
        ps[t] += u;
        __syncthreads();
    }
    if (t < NB) bucket_base[t] = ps[t] - v;
    if (t == 1023) bucket_base[NB] = ps[1023];
}

// A3: bsort: counting-sort the block's CHUNK edges by bucket in LDS, then
// flush sequentially so consecutive lanes write consecutive addresses
// within bucket runs (~10-13 line transactions per wave store vs 64 for
// the old direct scatter). LDS ~94 KB -> 1 block/CU, 8 waves.
__global__ __launch_bounds__(512) void bsort_kernel(const int* __restrict__ row,
                                                    const int* __restrict__ col,
                                                    const float* __restrict__ vals,
                                                    const int* __restrict__ bh2,
                                                    const int* __restrict__ bucket_base,
                                                    int2* __restrict__ bedge, int NB, int E) {
    __shared__ int2 sedge[CHUNK];            // 64 KB sorted edges
    __shared__ unsigned short sbkt[CHUNK];   // 16 KB slot -> bucket
    __shared__ int lhist[1024];              // hist, then reused as fill ctr
    __shared__ int lscan[1024];              // exclusive scan of hist
    __shared__ int lbase[1024];              // global dest base per bucket
    __shared__ int ps[512];
    int t = threadIdx.x, blk = blockIdx.x;
    int base = blk * CHUNK;
    int end = base + CHUNK; if (end > E) end = E;
    int n = end - base;
    for (int i = t; i < NB; i += 512) {
        lhist[i] = 0;
        lbase[i] = bucket_base[i] + bh2[(size_t)blk * NB + i];
    }
    __syncthreads();
    // pass 1: histogram
    for (int i = base + t; i < end; i += 512)
        atomicAdd(&lhist[row[i] >> RSH], 1);
    __syncthreads();
    // exclusive scan lhist[0..NB) -> lscan (512 threads, 2 entries each)
    int e0 = 2 * t, e1 = 2 * t + 1;
    int v0 = (e0 < NB) ? lhist[e0] : 0;
    int v1 = (e1 < NB) ? lhist[e1] : 0;
    int tsum = v0 + v1;
    ps[t] = tsum;
    __syncthreads();
    for (int off = 1; off < 512; off <<= 1) {
        int v = (t >= off) ? ps[t - off] : 0;
        __syncthreads();
        ps[t] += v;
        __syncthreads();
    }
    int pre = ps[t] - tsum;
    if (e0 < NB) lscan[e0] = pre;
    if (e1 < NB) lscan[e1] = pre + v0;
    __syncthreads();
    // reuse lhist as fill counters
    for (int i = t; i < NB; i += 512) lhist[i] = 0;
    __syncthreads();
    // pass 2: scatter into sorted LDS slots
    for (int i = base + t; i < end; i += 512) {
        int r = row[i];
        int b = r >> RSH;
        int p = atomicAdd(&lhist[b], 1);
        int slot = lscan[b] + p;
        sedge[slot] = make_int2(((r & (RPB - 1)) << 17) | col[i], __float_as_int(vals[i]));
        sbkt[slot] = (unsigned short)b;
    }
    __syncthreads();
    // flush: lane i writes sorted slot i -> run-contiguous global addresses
    for (int i = t; i < n; i += 512) {
        int b = sbkt[i];
        bedge[lbase[b] + (i - lscan[b])] = sedge[i];
    }
}

// Deg: block per bucket; LDS float accumulators; fused dinv. (R5-proven)
__global__ __launch_bounds__(256) void deg_kernel(const int2* __restrict__ bedge,
                                                  const int* __restrict__ bucket_base,
                                                  float* __restrict__ dinv, int N) {
    __shared__ float acc[RPB];
    int b = blockIdx.x, t = threadIdx.x;
    if (t < RPB) acc[t] = 0.f;
    __syncthreads();
    int s = bucket_base[b], e = bucket_base[b + 1];
    for (int i = s + t; i < e; i += 256) {
        int2 ed = bedge[i];
        atomicAdd(&acc[ed.x >> 17], __int_as_float(ed.y));
    }
    __syncthreads();
    if (t < RPB) {
        int r = b * RPB + t;
        if (r < N) {
            float d = acc[t];
            dinv[r] = (d > 0.f) ? (1.0f / sqrtf(d)) : 0.f;
        }
    }
}

// w[256][256] -> wT[256][256] (one-time, 256 KB)
__global__ __launch_bounds__(256) void transpose_kernel(const float* __restrict__ w,
                                                        float* __restrict__ wT) {
    __shared__ float tile[32][33];
    int bx = blockIdx.x * 32, by = blockIdx.y * 32;
    int tx = threadIdx.x, ty = threadIdx.y;  // dim(32,8)
    for (int j = ty; j < 32; j += 8) tile[j][tx] = w[(by + j) * DF + bx + tx];
    __syncthreads();
    for (int j = ty; j < 32; j += 8) wT[(bx + j) * DF + by + tx] = tile[tx][j];
}

// MFMA bf16 GEMM: h'[r,:] = bf16( dinv[r] * (x[r,:] @ w) )
// 128x256 tile (x read ONCE), BK=32, 4 waves in 2x2, each wave 64x128 =
// 4x8 MFMA 16x16x32. LDS stride 40 shorts breaks bank conflicts.
__global__ __launch_bounds__(256, 2) void gemm_kernel(const float* __restrict__ x,
                                                      const float* __restrict__ wT,
                                                      const float* __restrict__ dinv,
                                                      unsigned short* __restrict__ h, int N) {
    __shared__ unsigned short Al[128 * LSTR];   // 10 KB
    __shared__ unsigned short Bl[256 * LSTR];   // 20 KB
    int tid = threadIdx.x;
    int by = blockIdx.x;
    int wv = tid >> 6, lane = tid & 63;
    int wr = wv >> 1, wc = wv & 1;
    int q = lane >> 4, mi = lane & 15;

    f32x4 acc[4][8];
#pragma unroll
    for (int i = 0; i < 4; ++i)
#pragma unroll
        for (int j = 0; j < 8; ++j) acc[i][j] = (f32x4){0.f, 0.f, 0.f, 0.f};

    int srow = tid >> 1;           // 0..127
    int sseg = (tid & 1) * 16;     // k offset 0 or 16
    int axrow = by * 128 + srow; if (axrow >= N) axrow = N - 1;
    const float* ax = x + (long)axrow * DF + sseg;
    const float* bxp = wT + (long)tid * DF;         // thread t stages wT row t
    unsigned short* Aw = &Al[srow * LSTR + sseg];
    unsigned short* Bw = &Bl[tid * LSTR];

    for (int kk = 0; kk < DF; kk += 32) {
        float4 a0 = *(const float4*)(ax + kk);
        float4 a1 = *(const float4*)(ax + kk + 4);
        float4 a2 = *(const float4*)(ax + kk + 8);
        float4 a3 = *(const float4*)(ax + kk + 12);
        float4 b0 = *(const float4*)(bxp + kk);
        float4 b1 = *(const float4*)(bxp + kk + 4);
        float4 b2 = *(const float4*)(bxp + kk + 8);
        float4 b3 = *(const float4*)(bxp + kk + 12);
        float4 b4 = *(const float4*)(bxp + kk + 16);
        float4 b5 = *(const float4*)(bxp + kk + 20);
        float4 b6 = *(const float4*)(bxp + kk + 24);
        float4 b7 = *(const float4*)(bxp + kk + 28);
        __syncthreads();   // previous iteration's frag reads complete
        uint4 pa;
        pa.x = pack2(a0.x, a0.y); pa.y = pack2(a0.z, a0.w);
        pa.z = pack2(a1.x, a1.y); pa.w = pack2(a1.z, a1.w);
        *(uint4*)Aw = pa;
        pa.x = pack2(a2.x, a2.y); pa.y = pack2(a2.z, a2.w);
        pa.z = pack2(a3.x, a3.y); pa.w = pack2(a3.z, a3.w);
        *(uint4*)(Aw + 8) = pa;
        uint4 pb;
        pb.x = pack2(b0.x, b0.y); pb.y = pack2(b0.z, b0.w);
        pb.z = pack2(b1.x, b1.y); pb.w = pack2(b1.z, b1.w);
        *(uint4*)Bw = pb;
        pb.x = pack2(b2.x, b2.y); pb.y = pack2(b2.z, b2.w);
        pb.z = pack2(b3.x, b3.y); pb.w = pack2(b3.z, b3.w);
        *(uint4*)(Bw + 8) = pb;
        pb.x = pack2(b4.x, b4.y); pb.y = pack2(b4.z, b4.w);
        pb.z = pack2(b5.x, b5.y); pb.w = pack2(b5.z, b5.w);
        *(uint4*)(Bw + 16) = pb;
        pb.x = pack2(b6.x, b6.y); pb.y = pack2(b6.z, b6.w);
        pb.z = pack2(b7.x, b7.y); pb.w = pack2(b7.z, b7.w);
        *(uint4*)(Bw + 24) = pb;
        __syncthreads();   // tiles ready

        short8 af[4];
#pragma unroll
        for (int i = 0; i < 4; ++i)
            af[i] = *(const short8*)&Al[(wr * 64 + i * 16 + mi) * LSTR + q * 8];
#pragma unroll
        for (int j = 0; j < 8; ++j) {
            short8 bfj = *(const short8*)&Bl[(wc * 128 + j * 16 + mi) * LSTR + q * 8];
#pragma unroll
            for (int i = 0; i < 4; ++i)
                acc[i][j] = __builtin_amdgcn_mfma_f32_16x16x32_bf16(af[i], bfj, acc[i][j], 0, 0, 0);
        }
    }

    // C/D layout: col = lane&15, row = (lane>>4)*4 + reg   [verified m89/m91]
#pragma unroll
    for (int i = 0; i < 4; ++i) {
        int base_row = by * 128 + wr * 64 + i * 16 + q * 4;
#pragma unroll
        for (int r = 0; r < 4; ++r) {
            int rg = base_row + r;
            if (rg < N) {
                float dv = dinv[rg];
#pragma unroll
                for (int j = 0; j < 8; ++j) {
                    int cg = wc * 128 + j * 16 + mi;
                    h[(long)rg * DF + cg] = f2bf(dv * acc[i][j][r]);
                }
            }
        }
    }
}

// aggB: block per bucket. Counting-sort bucket edges into LDS, then one wave
// per row: split-wave gather. (R5-proven version: sort is hidden under the
// path-saturated gather.)
__global__ __launch_bounds__(256) void aggb_kernel(const unsigned short* __restrict__ h,
                                                   const int2* __restrict__ bedge,
                                                   const int* __restrict__ bucket_base,
                                                   const float* __restrict__ dinv,
                                                   const float* __restrict__ bias,
                                                   float* __restrict__ out, int N) {
    __shared__ int2 ledge[CAP];
    __shared__ int cnt[RPB];
    __shared__ int lrs[RPB + 1];
    __shared__ int lfill[RPB];
    int b = blockIdx.x, t = threadIdx.x;
    int s = bucket_base[b], e = bucket_base[b + 1];
    int tot = e - s;
    int cap_end = s + (tot < CAP ? tot : CAP);
    if (t < RPB) { cnt[t] = 0; lfill[t] = 0; }
    __syncthreads();
    // phase 1: count by local row
    for (int i = s + t; i < cap_end; i += 256)
        atomicAdd(&cnt[bedge[i].x >> 17], 1);
    __syncthreads();
    // exclusive scan cnt -> lrs (lrs[RPB] = total)
    int myc = 0;
    if (t < RPB) { myc = cnt[t]; lrs[t] = myc; }
    __syncthreads();
    for (int off = 1; off < RPB; off <<= 1) {
        int v = (t < RPB && t >= off) ? lrs[t - off] : 0;
        __syncthreads();
        if (t < RPB) lrs[t] += v;
        __syncthreads();
    }
    if (t < RPB) {
        int iv = lrs[t];
        lrs[t] = iv - myc;
        if (t == RPB - 1) lrs[RPB] = iv;
    }
    __syncthreads();
    // phase 2: scatter into sorted LDS (L2-hot re-read)
    for (int i = s + t; i < cap_end; i += 256) {
        int2 ed = bedge[i];
        int rl = ed.x >> 17;
        int p = lrs[rl] + atomicAdd(&lfill[rl], 1);
        ledge[p] = make_int2(ed.x & 0x1FFFF, ed.y);
    }
    __syncthreads();
    // phase 3: wave per row
    int wv = t >> 6, lane = t & 63;
    int half = lane >> 5;
    int fl = (lane & 31) * 8;
    const unsigned short* hp = h + fl;
    for (int lr = wv; lr < RPB; lr += 4) {
        int r = b * RPB + lr;
        if (r >= N) break;
        int rs = lrs[lr], re = lrs[lr + 1];
        float a0 = 0, a1 = 0, a2 = 0, a3 = 0, a4 = 0, a5 = 0, a6 = 0, a7 = 0;
        int i = rs + half;
        for (; i + 6 < re; i += 8) {
            int2 e0 = ledge[i], e1 = ledge[i + 2], e2 = ledge[i + 4], e3 = ledge[i + 6];
            uint4 u0 = *(const uint4*)(hp + (long)e0.x * DF);
            uint4 u1 = *(const uint4*)(hp + (long)e1.x * DF);
            uint4 u2 = *(const uint4*)(hp + (long)e2.x * DF);
            uint4 u3 = *(const uint4*)(hp + (long)e3.x * DF);
            float v0 = __int_as_float(e0.y), v1 = __int_as_float(e1.y);
            float v2 = __int_as_float(e2.y), v3 = __int_as_float(e3.y);
            a0 += v0 * bflo(u0.x) + v1 * bflo(u1.x) + v2 * bflo(u2.x) + v3 * bflo(u3.x);
            a1 += v0 * bfhi(u0.x) + v1 * bfhi(u1.x) + v2 * bfhi(u2.x) + v3 * bfhi(u3.x);
            a2 += v0 * bflo(u0.y) + v1 * bflo(u1.y) + v2 * bflo(u2.y) + v3 * bflo(u3.y);
            a3 += v0 * bfhi(u0.y) + v1 * bfhi(u1.y) + v2 * bfhi(u2.y) + v3 * bfhi(u3.y);
            a4 += v0 * bflo(u0.z) + v1 * bflo(u1.z) + v2 * bflo(u2.z) + v3 * bflo(u3.z);
            a5 += v0 * bfhi(u0.z) + v1 * bfhi(u1.z) + v2 * bfhi(u2.z) + v3 * bfhi(u3.z);
            a6 += v0 * bflo(u0.w) + v1 * bflo(u1.w) + v2 * bflo(u2.w) + v3 * bflo(u3.w);
            a7 += v0 * bfhi(u0.w) + v1 * bfhi(u1.w) + v2 * bfhi(u2.w) + v3 * bfhi(u3.w);
        }
        for (; i < re; i += 2) {
            int2 e0 = ledge[i];
            float v0 = __int_as_float(e0.y);
            uint4 u0 = *(const uint4*)(hp + (long)e0.x * DF);
            a0 += v0 * bflo(u0.x); a1 += v0 * bfhi(u0.x);
            a2 += v0 * bflo(u0.y); a3 += v0 * bfhi(u0.y);
            a4 += v0 * bflo(u0.z); a5 += v0 * bfhi(u0.z);
            a6 += v0 * bflo(u0.w); a7 += v0 * bfhi(u0.w);
        }
        // overflow leftovers (normally empty): filter unsorted global tail
        for (int j = cap_end + half; j < e; j += 2) {
            int2 ed = bedge[j];
            if ((ed.x >> 17) == lr) {
                float v0 = __int_as_float(ed.y);
                uint4 u0 = *(const uint4*)(hp + (long)(ed.x & 0x1FFFF) * DF);
                a0 += v0 * bflo(u0.x); a1 += v0 * bfhi(u0.x);
                a2 += v0 * bflo(u0.y); a3 += v0 * bfhi(u0.y);
                a4 += v0 * bflo(u0.z); a5 += v0 * bfhi(u0.z);
                a6 += v0 * bflo(u0.w); a7 += v0 * bfhi(u0.w);
            }
        }
        a0 += __shfl_xor(a0, 32); a1 += __shfl_xor(a1, 32);
        a2 += __shfl_xor(a2, 32); a3 += __shfl_xor(a3, 32);
        a4 += __shfl_xor(a4, 32); a5 += __shfl_xor(a5, 32);
        a6 += __shfl_xor(a6, 32); a7 += __shfl_xor(a7, 32);
        if (half == 0) {
            float dr = dinv[r];
            float4 b0 = *(const float4*)(bias + fl);
            float4 b1 = *(const float4*)(bias + fl + 4);
            float4 o0, o1;
            o0.x = fmaxf(fmaf(dr, a0, b0.x), 0.f);
            o0.y = fmaxf(fmaf(dr, a1, b0.y), 0.f);
            o0.z = fmaxf(fmaf(dr, a2, b0.z), 0.f);
            o0.w = fmaxf(fmaf(dr, a3, b0.w), 0.f);
            o1.x = fmaxf(fmaf(dr, a4, b1.x), 0.f);
            o1.y = fmaxf(fmaf(dr, a5, b1.y), 0.f);
            o1.z = fmaxf(fmaf(dr, a6, b1.z), 0.f);
            o1.w = fmaxf(fmaf(dr, a7, b1.w), 0.f);
            *(float4*)(out + (long)r * DF + fl) = o0;
            *(float4*)(out + (long)r * DF + fl + 4) = o1;
        }
    }
}

extern "C" void kernel_launch(void* const* d_in, const int* in_sizes, int n_in,
                              void* d_out, int out_size, void* d_ws, size_t ws_size,
                              hipStream_t stream) {
    const float* x   = (const float*)d_in[0];
    const int* erow  = (const int*)d_in[1];
    const int* ecol  = (const int*)d_in[2];
    const float* ev  = (const float*)d_in[3];
    const float* w   = (const float*)d_in[4];
    const float* b   = (const float*)d_in[5];
    float* out = (float*)d_out;

    int N = in_sizes[0] / DF;
    int E = in_sizes[1];
    int NB = (N + RPB - 1) >> RSH;          // 782 (<=1024 supported)
    int NBLK = (E + CHUNK - 1) / CHUNK;     // 391 (<=512 supported)

    char* ws = (char*)d_ws;
    size_t Ea8 = (((size_t)E * 8) + 255) & ~(size_t)255;         // bedge
    size_t Hs  = (((size_t)N * DF * 2) + 255) & ~(size_t)255;    // h
    size_t Na  = (((size_t)N * 4) + 255) & ~(size_t)255;

    // Layout (~77.5 MB total; bh1/bh2 alias h — dead before gemm):
    int2* bedge = (int2*)ws;
    char* reg2 = ws + Ea8;
    unsigned short* h = (unsigned short*)reg2;
    int* bh1 = (int*)reg2;                   // alias of h (A1..A3 only)
    int* bh2 = bh1 + (size_t)NB * NBLK;      // alias of h (A1..A3 only)
    char* reg3 = reg2 + Hs;
    float* wT = (float*)reg3;
    float* dinv = (float*)(reg3 + 262144);
    int* buckettot = (int*)(reg3 + 262144 + Na);
    int* bucket_base = (int*)(reg3 + 262144 + Na + 8192);

    bhist_kernel<<<NBLK, 256, 0, stream>>>(erow, bh1, NB, NBLK, E);
    bscan_kernel<<<NB, 256, 0, stream>>>(bh1, bh2, buckettot, NB, NBLK);
    btot_kernel<<<1, 1024, 0, stream>>>(buckettot, bucket_base, NB);
    bsort_kernel<<<NBLK, 512, 0, stream>>>(erow, ecol, ev, bh2, bucket_base, bedge, NB, E);
    deg_kernel<<<NB, 256, 0, stream>>>(bedge, bucket_base, dinv, N);
    transpose_kernel<<<dim3(8, 8), dim3(32, 8), 0, stream>>>(w, wT);
    gemm_kernel<<<dim3((N + 127) / 128), 256, 0, stream>>>(x, wT, dinv, h, N);
    aggb_kernel<<<NB, 256, 0, stream>>>(h, bedge, bucket_base, dinv, b, out, N);
}

// Round 5
// 589.238 us; speedup vs baseline: 1.2634x; 1.0024x over previous
//
#include <hip/hip_runtime.h>
#include <hip/hip_bf16.h>

// GCN layer: out = relu( (D^-1/2 A D^-1/2) (x @ w) + b )
//
// R10 (from R9's 590.7 us):
//   R9 refuted the bscatter-transaction theory (bsort == bscatter, -4us).
//   Re-solved budget: gemm ~= 70 us robustly (R5/R6/R7/R9 system), which is
//   3x over every pipe model (mem 26, LDS 12, MFMA 2) -> latency/structure
//   bound: per-K-step serial {fp32 load -> barrier -> pack -> LDS write ->
//   barrier -> LDS read -> MFMA} at 2 blocks/CU with ~176+ live VGPRs.
//   FIX: gemm v2 with ZERO LDS / ZERO barriers:
//     - B (wbT, 128 KB bf16) is L2-resident -> load frags direct from L2.
//     - A fp32 direct from HBM with a 1-iter register rotate (latency hides
//       under MFMA), converted in-reg via v_cvt_pk_bf16_f32.
//     - transpose_kernel now emits bf16 wbT (same RNE rounding as before).
//   aggb (250 us) is at its path-saturated floor (753 MB past-L2 gather at
//   ~3.5 TB/s); prep/bsort unchanged from R9.

#define DF   256   // D_FEAT == FILTERS == 256
#define RSH  7
#define RPB  128   // rows per bucket = 1<<RSH
#define CAP  4800  // LDS edge capacity per bucket (mean 4096, sd 64 -> 11 sigma)
#define CHUNK 8192 // edges per block in A1/A3

typedef __attribute__((ext_vector_type(8))) short short8;  // 8 x bf16
typedef __attribute__((ext_vector_type(4))) float f32x4;

__device__ __forceinline__ unsigned short f2bf(float f) {
    unsigned int u = __float_as_uint(f);
    unsigned int r = (u + 0x7fffu + ((u >> 16) & 1u)) >> 16;  // RNE
    return (unsigned short)r;
}
// v_cvt_pk_bf16_f32: D.lo = bf16(a) RNE, D.hi = bf16(b) RNE (gfx950)
__device__ __forceinline__ unsigned int pack2(float a, float b) {
    unsigned int r;
    asm("v_cvt_pk_bf16_f32 %0, %1, %2" : "=v"(r) : "v"(a), "v"(b));
    return r;
}
__device__ __forceinline__ float bflo(unsigned int u) { return __uint_as_float(u << 16); }
__device__ __forceinline__ float bfhi(unsigned int u) { return __uint_as_float(u & 0xffff0000u); }

// A1: per-block bucket histogram; layout bh1[bucket][block] so bscan reads coalesced.
__global__ __launch_bounds__(256) void bhist_kernel(const int* __restrict__ row,
                                                    int* __restrict__ bh1, int NB, int NBLK, int E) {
    __shared__ int hist[1024];
    int t = threadIdx.x;
    for (int i = t; i < NB; i += 256) hist[i] = 0;
    __syncthreads();
    int base = blockIdx.x * CHUNK;
    int end = base + CHUNK; if (end > E) end = E;
    for (int i = base + t; i < end; i += 256)
        atomicAdd(&hist[row[i] >> RSH], 1);
    __syncthreads();
    for (int i = t; i < NB; i += 256)
        bh1[(size_t)i * NBLK + blockIdx.x] = hist[i];
}

// A2: per bucket (blockIdx), exclusive scan over NBLK block counts (NBLK <= 512).
__global__ __launch_bounds__(256) void bscan_kernel(const int* __restrict__ bh1,
                                                    int* __restrict__ bh2,
                                                    int* __restrict__ buckettot, int NB, int NBLK) {
    __shared__ int ps[256];
    int b = blockIdx.x, t = threadIdx.x;
    int e0 = 2 * t, e1 = 2 * t + 1;
    int v0 = (e0 < NBLK) ? bh1[(size_t)b * NBLK + e0] : 0;
    int v1 = (e1 < NBLK) ? bh1[(size_t)b * NBLK + e1] : 0;
    int tsum = v0 + v1;
    ps[t] = tsum;
    __syncthreads();
    for (int off = 1; off < 256; off <<= 1) {
        int v = (t >= off) ? ps[t - off] : 0;
        __syncthreads();
        ps[t] += v;
        __syncthreads();
    }
    int pre = ps[t] - tsum;  // exclusive
    if (e0 < NBLK) bh2[(size_t)e0 * NB + b] = pre;
    if (e1 < NBLK) bh2[(size_t)e1 * NB + b] = pre + v0;
    if (t == 255) buckettot[b] = ps[255];
}

// A2b: single block, exclusive scan of buckettot[0..NB) -> bucket_base[0..NB]
__global__ __launch_bounds__(1024) void btot_kernel(const int* __restrict__ buckettot,
                                                    int* __restrict__ bucket_base, int NB) {
    __shared__ int ps[1024];
    int t = threadIdx.x;
    int v = (t < NB) ? buckettot[t] : 0;
    ps[t] = v;
    __syncthreads();
    for (int off = 1; off < 1024; off <<= 1) {
        int u = (t >= off) ? ps[t - off] : 0;
        __syncthreads();
        ps[t] += u;
        __syncthreads();
    }
    if (t < NB) bucket_base[t] = ps[t] - v;
    if (t == 1023) bucket_base[NB] = ps[1023];
}

// A3: bsort: counting-sort the block's CHUNK edges by bucket in LDS, then
// flush sequentially (run-contiguous global writes). LDS ~94 KB.
__global__ __launch_bounds__(512) void bsort_kernel(const int* __restrict__ row,
                                                    const int* __restrict__ col,
                                                    const float* __restrict__ vals,
                                                    const int* __restrict__ bh2,
                                                    const int* __restrict__ bucket_base,
                                                    int2* __restrict__ bedge, int NB, int E) {
    __shared__ int2 sedge[CHUNK];            // 64 KB sorted edges
    __shared__ unsigned short sbkt[CHUNK];   // 16 KB slot -> bucket
    __shared__ int lhist[1024];              // hist, then reused as fill ctr
    __shared__ int lscan[1024];              // exclusive scan of hist
    __shared__ int lbase[1024];              // global dest base per bucket
    __shared__ int ps[512];
    int t = threadIdx.x, blk = blockIdx.x;
    int base = blk * CHUNK;
    int end = base + CHUNK; if (end > E) end = E;
    int n = end - base;
    for (int i = t; i < NB; i += 512) {
        lhist[i] = 0;
        lbase[i] = bucket_base[i] + bh2[(size_t)blk * NB + i];
    }
    __syncthreads();
    for (int i = base + t; i < end; i += 512)
        atomicAdd(&lhist[row[i] >> RSH], 1);
    __syncthreads();
    int e0 = 2 * t, e1 = 2 * t + 1;
    int v0 = (e0 < NB) ? lhist[e0] : 0;
    int v1 = (e1 < NB) ? lhist[e1] : 0;
    int tsum = v0 + v1;
    ps[t] = tsum;
    __syncthreads();
    for (int off = 1; off < 512; off <<= 1) {
        int v = (t >= off) ? ps[t - off] : 0;
        __syncthreads();
        ps[t] += v;
        __syncthreads();
    }
    int pre = ps[t] - tsum;
    if (e0 < NB) lscan[e0] = pre;
    if (e1 < NB) lscan[e1] = pre + v0;
    __syncthreads();
    for (int i = t; i < NB; i += 512) lhist[i] = 0;
    __syncthreads();
    for (int i = base + t; i < end; i += 512) {
        int r = row[i];
        int b = r >> RSH;
        int p = atomicAdd(&lhist[b], 1);
        int slot = lscan[b] + p;
        sedge[slot] = make_int2(((r & (RPB - 1)) << 17) | col[i], __float_as_int(vals[i]));
        sbkt[slot] = (unsigned short)b;
    }
    __syncthreads();
    for (int i = t; i < n; i += 512) {
        int b = sbkt[i];
        bedge[lbase[b] + (i - lscan[b])] = sedge[i];
    }
}

// Deg: block per bucket; LDS float accumulators; fused dinv. (R5-proven)
__global__ __launch_bounds__(256) void deg_kernel(const int2* __restrict__ bedge,
                                                  const int* __restrict__ bucket_base,
                                                  float* __restrict__ dinv, int N) {
    __shared__ float acc[RPB];
    int b = blockIdx.x, t = threadIdx.x;
    if (t < RPB) acc[t] = 0.f;
    __syncthreads();
    int s = bucket_base[b], e = bucket_base[b + 1];
    for (int i = s + t; i < e; i += 256) {
        int2 ed = bedge[i];
        atomicAdd(&acc[ed.x >> 17], __int_as_float(ed.y));
    }
    __syncthreads();
    if (t < RPB) {
        int r = b * RPB + t;
        if (r < N) {
            float d = acc[t];
            dinv[r] = (d > 0.f) ? (1.0f / sqrtf(d)) : 0.f;
        }
    }
}

// w[256][256] fp32 -> wbT[256][256] bf16 (one-time; RNE identical to pack2)
__global__ __launch_bounds__(256) void transpose_kernel(const float* __restrict__ w,
                                                        unsigned short* __restrict__ wbT) {
    __shared__ float tile[32][33];
    int bx = blockIdx.x * 32, by = blockIdx.y * 32;
    int tx = threadIdx.x, ty = threadIdx.y;  // dim(32,8)
    for (int j = ty; j < 32; j += 8) tile[j][tx] = w[(by + j) * DF + bx + tx];
    __syncthreads();
    for (int j = ty; j < 32; j += 8) wbT[(bx + j) * DF + by + tx] = f2bf(tile[tx][j]);
}

// MFMA bf16 GEMM v2: h'[r,:] = bf16( dinv[r] * (x[r,:] @ w) )
// ZERO LDS, ZERO barriers. 128x256 tile, 4 waves 2x2, each 64x128 = 4x8
// MFMA 16x16x32. B-frags loaded direct from L2-resident wbT (128 KB);
// A fp32 loaded direct from HBM with 1-iter register rotate, converted
// in-reg via v_cvt_pk_bf16_f32 (16 VALU/K-step, hides under MFMA).
__global__ __launch_bounds__(256, 2) void gemm_kernel(const float* __restrict__ x,
                                                      const unsigned short* __restrict__ wbT,
                                                      const float* __restrict__ dinv,
                                                      unsigned short* __restrict__ h, int N) {
    int tid = threadIdx.x;
    int by = blockIdx.x;
    int wv = tid >> 6, lane = tid & 63;
    int wr = wv >> 1, wc = wv & 1;
    int q = lane >> 4, mi = lane & 15;

    f32x4 acc[4][8];
#pragma unroll
    for (int i = 0; i < 4; ++i)
#pragma unroll
        for (int j = 0; j < 8; ++j) acc[i][j] = (f32x4){0.f, 0.f, 0.f, 0.f};

    // per-lane row pointers (A rows clamped for tail block)
    const float* axp[4];
#pragma unroll
    for (int i = 0; i < 4; ++i) {
        int r = by * 128 + wr * 64 + i * 16 + mi;
        if (r >= N) r = N - 1;
        axp[i] = x + (long)r * DF + q * 8;
    }
    const unsigned short* bwp[8];
#pragma unroll
    for (int j = 0; j < 8; ++j)
        bwp[j] = wbT + (long)(wc * 128 + j * 16 + mi) * DF + q * 8;

    // prologue: A fp32 for kk=0 -> bf16 frags
    short8 af[4];
    {
        float4 p0[4], p1[4];
#pragma unroll
        for (int i = 0; i < 4; ++i) {
            p0[i] = *(const float4*)(axp[i]);
            p1[i] = *(const float4*)(axp[i] + 4);
        }
#pragma unroll
        for (int i = 0; i < 4; ++i) {
            uint4 pk;
            pk.x = pack2(p0[i].x, p0[i].y); pk.y = pack2(p0[i].z, p0[i].w);
            pk.z = pack2(p1[i].x, p1[i].y); pk.w = pack2(p1[i].z, p1[i].w);
            af[i] = *(short8*)&pk;
        }
    }

    for (int t = 0; t < 8; ++t) {
        int kk = t * 32;
        // B frags for this K-step (L2 hits after first block touches wbT)
        uint4 bw[8];
#pragma unroll
        for (int j = 0; j < 8; ++j)
            bw[j] = *(const uint4*)(bwp[j] + kk);
        // A prefetch for next K-step (HBM latency hides under MFMAs below)
        float4 n0[4], n1[4];
        if (t < 7) {
#pragma unroll
            for (int i = 0; i < 4; ++i) {
                n0[i] = *(const float4*)(axp[i] + kk + 32);
                n1[i] = *(const float4*)(axp[i] + kk + 36);
            }
        }
#pragma unroll
        for (int j = 0; j < 8; ++j) {
            short8 bfj = *(short8*)&bw[j];
#pragma unroll
            for (int i = 0; i < 4; ++i)
                acc[i][j] = __builtin_amdgcn_mfma_f32_16x16x32_bf16(af[i], bfj, acc[i][j], 0, 0, 0);
        }
        if (t < 7) {
#pragma unroll
            for (int i = 0; i < 4; ++i) {
                uint4 pk;
                pk.x = pack2(n0[i].x, n0[i].y); pk.y = pack2(n0[i].z, n0[i].w);
                pk.z = pack2(n1[i].x, n1[i].y); pk.w = pack2(n1[i].z, n1[i].w);
                af[i] = *(short8*)&pk;
            }
        }
    }

    // C/D layout: col = lane&15, row = (lane>>4)*4 + reg   [verified m89/m91]
#pragma unroll
    for (int i = 0; i < 4; ++i) {
        int base_row = by * 128 + wr * 64 + i * 16 + q * 4;
#pragma unroll
        for (int r = 0; r < 4; ++r) {
            int rg = base_row + r;
            if (rg < N) {
                float dv = dinv[rg];
#pragma unroll
                for (int j = 0; j < 8; ++j) {
                    int cg = wc * 128 + j * 16 + mi;
                    h[(long)rg * DF + cg] = f2bf(dv * acc[i][j][r]);
                }
            }
        }
    }
}

// aggB: block per bucket. Counting-sort bucket edges into LDS, then one wave
// per row: split-wave gather. (R5-proven; sort hidden under gather saturation.)
__global__ __launch_bounds__(256) void aggb_kernel(const unsigned short* __restrict__ h,
                                                   const int2* __restrict__ bedge,
                                                   const int* __restrict__ bucket_base,
                                                   const float* __restrict__ dinv,
                                                   const float* __restrict__ bias,
                                                   float* __restrict__ out, int N) {
    __shared__ int2 ledge[CAP];
    __shared__ int cnt[RPB];
    __shared__ int lrs[RPB + 1];
    __shared__ int lfill[RPB];
    int b = blockIdx.x, t = threadIdx.x;
    int s = bucket_base[b], e = bucket_base[b + 1];
    int tot = e - s;
    int cap_end = s + (tot < CAP ? tot : CAP);
    if (t < RPB) { cnt[t] = 0; lfill[t] = 0; }
    __syncthreads();
    for (int i = s + t; i < cap_end; i += 256)
        atomicAdd(&cnt[bedge[i].x >> 17], 1);
    __syncthreads();
    int myc = 0;
    if (t < RPB) { myc = cnt[t]; lrs[t] = myc; }
    __syncthreads();
    for (int off = 1; off < RPB; off <<= 1) {
        int v = (t < RPB && t >= off) ? lrs[t - off] : 0;
        __syncthreads();
        if (t < RPB) lrs[t] += v;
        __syncthreads();
    }
    if (t < RPB) {
        int iv = lrs[t];
        lrs[t] = iv - myc;
        if (t == RPB - 1) lrs[RPB] = iv;
    }
    __syncthreads();
    for (int i = s + t; i < cap_end; i += 256) {
        int2 ed = bedge[i];
        int rl = ed.x >> 17;
        int p = lrs[rl] + atomicAdd(&lfill[rl], 1);
        ledge[p] = make_int2(ed.x & 0x1FFFF, ed.y);
    }
    __syncthreads();
    int wv = t >> 6, lane = t & 63;
    int half = lane >> 5;
    int fl = (lane & 31) * 8;
    const unsigned short* hp = h + fl;
    for (int lr = wv; lr < RPB; lr += 4) {
        int r = b * RPB + lr;
        if (r >= N) break;
        int rs = lrs[lr], re = lrs[lr + 1];
        float a0 = 0, a1 = 0, a2 = 0, a3 = 0, a4 = 0, a5 = 0, a6 = 0, a7 = 0;
        int i = rs + half;
        for (; i + 6 < re; i += 8) {
            int2 e0 = ledge[i], e1 = ledge[i + 2], e2 = ledge[i + 4], e3 = ledge[i + 6];
            uint4 u0 = *(const uint4*)(hp + (long)e0.x * DF);
            uint4 u1 = *(const uint4*)(hp + (long)e1.x * DF);
            uint4 u2 = *(const uint4*)(hp + (long)e2.x * DF);
            uint4 u3 = *(const uint4*)(hp + (long)e3.x * DF);
            float v0 = __int_as_float(e0.y), v1 = __int_as_float(e1.y);
            float v2 = __int_as_float(e2.y), v3 = __int_as_float(e3.y);
            a0 += v0 * bflo(u0.x) + v1 * bflo(u1.x) + v2 * bflo(u2.x) + v3 * bflo(u3.x);
            a1 += v0 * bfhi(u0.x) + v1 * bfhi(u1.x) + v2 * bfhi(u2.x) + v3 * bfhi(u3.x);
            a2 += v0 * bflo(u0.y) + v1 * bflo(u1.y) + v2 * bflo(u2.y) + v3 * bflo(u3.y);
            a3 += v0 * bfhi(u0.y) + v1 * bfhi(u1.y) + v2 * bfhi(u2.y) + v3 * bfhi(u3.y);
            a4 += v0 * bflo(u0.z) + v1 * bflo(u1.z) + v2 * bflo(u2.z) + v3 * bflo(u3.z);
            a5 += v0 * bfhi(u0.z) + v1 * bfhi(u1.z) + v2 * bfhi(u2.z) + v3 * bfhi(u3.z);
            a6 += v0 * bflo(u0.w) + v1 * bflo(u1.w) + v2 * bflo(u2.w) + v3 * bflo(u3.w);
            a7 += v0 * bfhi(u0.w) + v1 * bfhi(u1.w) + v2 * bfhi(u2.w) + v3 * bfhi(u3.w);
        }
        for (; i < re; i += 2) {
            int2 e0 = ledge[i];
            float v0 = __int_as_float(e0.y);
            uint4 u0 = *(const uint4*)(hp + (long)e0.x * DF);
            a0 += v0 * bflo(u0.x); a1 += v0 * bfhi(u0.x);
            a2 += v0 * bflo(u0.y); a3 += v0 * bfhi(u0.y);
            a4 += v0 * bflo(u0.z); a5 += v0 * bfhi(u0.z);
            a6 += v0 * bflo(u0.w); a7 += v0 * bfhi(u0.w);
        }
        for (int j = cap_end + half; j < e; j += 2) {
            int2 ed = bedge[j];
            if ((ed.x >> 17) == lr) {
                float v0 = __int_as_float(ed.y);
                uint4 u0 = *(const uint4*)(hp + (long)(ed.x & 0x1FFFF) * DF);
                a0 += v0 * bflo(u0.x); a1 += v0 * bfhi(u0.x);
                a2 += v0 * bflo(u0.y); a3 += v0 * bfhi(u0.y);
                a4 += v0 * bflo(u0.z); a5 += v0 * bfhi(u0.z);
                a6 += v0 * bflo(u0.w); a7 += v0 * bfhi(u0.w);
            }
        }
        a0 += __shfl_xor(a0, 32); a1 += __shfl_xor(a1, 32);
        a2 += __shfl_xor(a2, 32); a3 += __shfl_xor(a3, 32);
        a4 += __shfl_xor(a4, 32); a5 += __shfl_xor(a5, 32);
        a6 += __shfl_xor(a6, 32); a7 += __shfl_xor(a7, 32);
        if (half == 0) {
            float dr = dinv[r];
            float4 b0 = *(const float4*)(bias + fl);
            float4 b1 = *(const float4*)(bias + fl + 4);
            float4 o0, o1;
            o0.x = fmaxf(fmaf(dr, a0, b0.x), 0.f);
            o0.y = fmaxf(fmaf(dr, a1, b0.y), 0.f);
            o0.z = fmaxf(fmaf(dr, a2, b0.z), 0.f);
            o0.w = fmaxf(fmaf(dr, a3, b0.w), 0.f);
            o1.x = fmaxf(fmaf(dr, a4, b1.x), 0.f);
            o1.y = fmaxf(fmaf(dr, a5, b1.y), 0.f);
            o1.z = fmaxf(fmaf(dr, a6, b1.z), 0.f);
            o1.w = fmaxf(fmaf(dr, a7, b1.w), 0.f);
            *(float4*)(out + (long)r * DF + fl) = o0;
            *(float4*)(out + (long)r * DF + fl + 4) = o1;
        }
    }
}

extern "C" void kernel_launch(void* const* d_in, const int* in_sizes, int n_in,
                              void* d_out, int out_size, void* d_ws, size_t ws_size,
                              hipStream_t stream) {
    const float* x   = (const float*)d_in[0];
    const int* erow  = (const int*)d_in[1];
    const int* ecol  = (const int*)d_in[2];
    const float* ev  = (const float*)d_in[3];
    const float* w   = (const float*)d_in[4];
    const float* b   = (const float*)d_in[5];
    float* out = (float*)d_out;

    int N = in_sizes[0] / DF;
    int E = in_sizes[1];
    int NB = (N + RPB - 1) >> RSH;          // 782 (<=1024 supported)
    int NBLK = (E + CHUNK - 1) / CHUNK;     // 391 (<=512 supported)

    char* ws = (char*)d_ws;
    size_t Ea8 = (((size_t)E * 8) + 255) & ~(size_t)255;         // bedge
    size_t Hs  = (((size_t)N * DF * 2) + 255) & ~(size_t)255;    // h
    size_t Na  = (((size_t)N * 4) + 255) & ~(size_t)255;

    // Layout (~77.5 MB total; bh1/bh2 alias h — dead before gemm):
    int2* bedge = (int2*)ws;
    char* reg2 = ws + Ea8;
    unsigned short* h = (unsigned short*)reg2;
    int* bh1 = (int*)reg2;                   // alias of h (A1..A3 only)
    int* bh2 = bh1 + (size_t)NB * NBLK;      // alias of h (A1..A3 only)
    char* reg3 = reg2 + Hs;
    unsigned short* wbT = (unsigned short*)reg3;   // 128 KB used of 256 KB slot
    float* dinv = (float*)(reg3 + 262144);
    int* buckettot = (int*)(reg3 + 262144 + Na);
    int* bucket_base = (int*)(reg3 + 262144 + Na + 8192);

    bhist_kernel<<<NBLK, 256, 0, stream>>>(erow, bh1, NB, NBLK, E);
    bscan_kernel<<<NB, 256, 0, stream>>>(bh1, bh2, buckettot, NB, NBLK);
    btot_kernel<<<1, 1024, 0, stream>>>(buckettot, bucket_base, NB);
    bsort_kernel<<<NBLK, 512, 0, stream>>>(erow, ecol, ev, bh2, bucket_base, bedge, NB, E);
    deg_kernel<<<NB, 256, 0, stream>>>(bedge, bucket_base, dinv, N);
    transpose_kernel<<<dim3(8, 8), dim3(32, 8), 0, stream>>>(w, wbT);
    gemm_kernel<<<dim3((N + 127) / 128), 256, 0, stream>>>(x, wbT, dinv, h, N);
    aggb_kernel<<<NB, 256, 0, stream>>>(h, bedge, bucket_base, dinv, b, out, N);
}